// Round 2
// baseline (824.020 us; speedup 1.0000x reference)
//
#include <hip/hip_runtime.h>

#define NIMG 16
#define NC 3
#define H 256
#define W 256
#define HW (H * W)
#define NS 25          // 5x5 per-pixel kernel
#define TH 32
#define TW 32
#define SRH (TH + 10)  // avg/max region: fac halo(2) + conv halo(3) each side
#define SRW (TW + 10)
#define MRH (TH + 4)   // q region: fac halo(2) each side
#define MRW (TW + 4)
#define NTHREADS 256
#define PPT ((TH * TW) / NTHREADS)  // 4

__global__ __launch_bounds__(NTHREADS, 4)
void reblur_fused(const float* __restrict__ blur_info,
                  const float* __restrict__ pp0,
                  const float* __restrict__ pp1,
                  const float* __restrict__ pp2,
                  const float* __restrict__ wt0,
                  const float* __restrict__ wt1,
                  const float* __restrict__ wt2,
                  float* __restrict__ out)
{
    __shared__ float s_avg[SRH * SRW];           // 7.1 KB
    __shared__ float s_mx[SRH * SRW];            // 7.1 KB
    __shared__ float q[NC][MRH * MRW];           // 15.6 KB  q = mask*blur
    __shared__ float wts[3][98];                 // avg weights (pre-scaled 1/25), then max

    const int tid = threadIdx.x;
    const int n  = blockIdx.z;
    const int h0 = blockIdx.y * TH;
    const int w0 = blockIdx.x * TW;

    for (int i = tid; i < 3 * 98; i += NTHREADS) {
        int b = i / 98, j = i % 98;
        const float* wp = (b == 0) ? wt0 : (b == 1) ? wt1 : wt2;
        wts[b][j] = wp[j] * (j < 49 ? 0.04f : 1.0f);   // fold 1/25 avg into weights
    }

    float acc[PPT][NC];
    #pragma unroll
    for (int k = 0; k < PPT; ++k)
        #pragma unroll
        for (int c = 0; c < NC; ++c) acc[k][c] = 0.f;

    const float* pps[3] = {pp0, pp1, pp2};
    __syncthreads();   // wts visible

    for (int b = 0; b < 3; ++b) {
        const float* pp = pps[b] + n * (NS * HW);

        // ---- step 1: channel sum & max over 42x42 halo region (sum pre-scaled via wts)
        for (int i = tid; i < SRH * SRW; i += NTHREADS) {
            int rr = i / SRW, cc = i % SRW;
            int gh = h0 - 5 + rr, gw = w0 - 5 + cc;
            float sum = 0.f, mx = 0.f;   // out-of-image => conv zero-padding of [avg,max]
            if ((unsigned)gh < H && (unsigned)gw < W) {
                const float* p = pp + gh * W + gw;
                float v0 = p[0];
                sum = v0; mx = v0;
                #pragma unroll
                for (int s = 1; s < NS; ++s) {
                    float v = p[s * HW];
                    sum += v; mx = fmaxf(mx, v);
                }
            }
            s_avg[i] = sum;
            s_mx[i]  = mx;
        }
        __syncthreads();

        // ---- step 2: 7x7 conv + sigmoid -> mask; q = mask * blur over 36x36 region.
        // Register-blocked 4 rows/item: 10 input rows cover 4 outputs (35 LDS reads/px).
        for (int wi = tid; wi < (MRH / 4) * MRW; wi += NTHREADS) {
            int rb = wi / MRW, cc = wi % MRW;
            int r0 = rb * 4;
            float a4[4] = {0.f, 0.f, 0.f, 0.f};
            #pragma unroll
            for (int j = 0; j < 10; ++j) {
                float av[7], mv[7];
                #pragma unroll
                for (int t = 0; t < 7; ++t) {
                    av[t] = s_avg[(r0 + j) * SRW + cc + t];
                    mv[t] = s_mx[(r0 + j) * SRW + cc + t];
                }
                const int klo = (j - 6) > 0 ? (j - 6) : 0;
                const int khi = j < 3 ? j : 3;
                #pragma unroll
                for (int k = klo; k <= khi; ++k) {
                    const int wr = (j - k) * 7;
                    #pragma unroll
                    for (int t = 0; t < 7; ++t)
                        a4[k] += av[t] * wts[b][wr + t] + mv[t] * wts[b][49 + wr + t];
                }
            }
            #pragma unroll
            for (int k = 0; k < 4; ++k) {
                float m = 1.f / (1.f + __expf(-a4[k]));
                int gh = h0 - 2 + r0 + k, gw = w0 - 2 + cc;
                bool inb = (unsigned)gh < H && (unsigned)gw < W;
                int gi = gh * W + gw;
                #pragma unroll
                for (int c = 0; c < NC; ++c) {
                    float bv = inb ? blur_info[(n * NC + c) * HW + gi] : 0.f;  // feat zero-pad
                    q[c][(r0 + k) * MRW + cc] = m * bv;
                }
            }
        }
        __syncthreads();

        // ---- step 3: acc += -q_center + sum_s pk_s * q_s  (sharp+blur folded)
        for (int k = 0; k < PPT; ++k) {
            int oi = tid + k * NTHREADS;
            int r = oi / TW, cc = oi % TW;
            const float* pk = pp + (h0 + r) * W + (w0 + cc);
            float pkv[NS];
            #pragma unroll
            for (int s = 0; s < NS; ++s) pkv[s] = pk[s * HW];   // L2-warm from step 1
            int qc = (r + 2) * MRW + cc + 2;
            float f0 = -q[0][qc], f1 = -q[1][qc], f2 = -q[2][qc];
            #pragma unroll
            for (int s = 0; s < NS; ++s) {
                const int dh = s / 5, dw = s % 5;
                const int qi = (r + dh) * MRW + cc + dw;
                f0 += pkv[s] * q[0][qi];
                f1 += pkv[s] * q[1][qi];
                f2 += pkv[s] * q[2][qi];
            }
            acc[k][0] += f0; acc[k][1] += f1; acc[k][2] += f2;
        }
        __syncthreads();   // q reads done before next branch's step-2 rewrites
    }

    const float inv3 = 1.f / 3.f;
    for (int k = 0; k < PPT; ++k) {
        int oi = tid + k * NTHREADS;
        int r = oi / TW, cc = oi % TW;
        int gi = (h0 + r) * W + (w0 + cc);
        #pragma unroll
        for (int c = 0; c < NC; ++c)
            out[(n * NC + c) * HW + gi] = blur_info[(n * NC + c) * HW + gi] + acc[k][c] * inv3;
    }
}

extern "C" void kernel_launch(void* const* d_in, const int* in_sizes, int n_in,
                              void* d_out, int out_size, void* d_ws, size_t ws_size,
                              hipStream_t stream) {
    dim3 grid(W / TW, H / TH, NIMG);   // 8 x 8 x 16 = 1024 blocks
    reblur_fused<<<grid, NTHREADS, 0, stream>>>(
        (const float*)d_in[0],
        (const float*)d_in[1], (const float*)d_in[2], (const float*)d_in[3],
        (const float*)d_in[4], (const float*)d_in[5], (const float*)d_in[6],
        (float*)d_out);
}